// Round 4
// baseline (1012.618 us; speedup 1.0000x reference)
//
#include <hip/hip_runtime.h>
#include <hip/hip_bf16.h>
#include <cstddef>

// LSTMCell fused: z = [u|h] @ [W|U]^T + bW + bE ; gates ; c/h update.
// fp32 in / fp32 out; bf16 MFMA internal, fp32 accum.
// GEMM view: M=16384, N=2048 (4 gates x 512), K=1024.
// R3: BM=256 x BH=64 (Neff=256), 512 thr / 8 waves (2M x 4H), BK=64.
//     Halves total L2/L3 load traffic (2GB -> 1GB) vs R2's 128x32 tile.
//     XCD swizzle: 512 blocks, 8 XCDs -> each XCD owns ONE h_tile, so its
//     1 MB fp32 weight slice is L2-resident. LDS XOR-swizzle kept (0 conflicts).

#define BDIM 16384
#define HDIM 512

typedef __attribute__((ext_vector_type(8))) short bf16x8;
typedef __attribute__((ext_vector_type(4))) float f32x4;

struct Params {
  const float* u;
  const float* h;
  const float* c;
  const float* W[4];   // Wi Wf Wg Wo  [512,512]
  const float* U[4];   // Ui Uf Ug Uo  [512,512]
  const float* bW[4];  // [512]
  const float* bE[4];  // [512]
  float* outh;
  float* outc;
};

__device__ __forceinline__ float sigmoidf_(float x) {
  return 1.0f / (1.0f + __expf(-x));
}

__device__ __forceinline__ bf16x8 cvt8(f32x4 a, f32x4 b) {
  bf16x8 r;
#pragma unroll
  for (int j = 0; j < 4; ++j) {
    __hip_bfloat16 t = __float2bfloat16(a[j]);
    r[j] = *reinterpret_cast<short*>(&t);
  }
#pragma unroll
  for (int j = 0; j < 4; ++j) {
    __hip_bfloat16 t = __float2bfloat16(b[j]);
    r[4 + j] = *reinterpret_cast<short*>(&t);
  }
  return r;
}

__launch_bounds__(512, 4)
__global__ void lstm_cell_kernel(Params p) {
  // LDS: A bf16 [256][64] (32 KB) + W bf16 [4][64][64] (32 KB), swizzled cols
  __shared__ char smem[65536];
  __shared__ float biasLDS[4][64];

  const int tid = threadIdx.x;
  const int w   = tid >> 6;   // 0..7
  const int l   = tid & 63;
  const int wm  = w >> 2;     // 0..1 : 128-row half
  const int wh  = w & 3;      // 0..3 : 16-hcol group

  // XCD-aware swizzle: nwg=512 (%8==0). XCD x gets blocks with h_tile==x.
  const int swz = (blockIdx.x & 7) * 64 + (blockIdx.x >> 3);
  const int m_tile = swz & 63;
  const int h_tile = swz >> 6;

  char* smemA = smem;          // [256 rows][128 B]
  char* smemW = smem + 32768;  // [4 gates][64 rows][128 B]

  const int rowA0 = m_tile * 256;
  const int nrow0 = h_tile * 64;

  if (tid < 256) {
    const int g = tid >> 6, hh = tid & 63;
    const int hc = nrow0 + hh;
    biasLDS[g][hh] = p.bW[g][hc] + p.bE[g][hc];
  }

  const int sr = tid >> 3;  // 0..63: row within each 64-row chunk
  const int sc = tid & 7;   // 0..7 : 16B slot within 128B row
  const int wcol = (sc * 16) ^ ((sr & 7) << 4);  // swizzled write column

  f32x4 acc[4][8] = {};  // [gate][m-frag] : 128 AGPRs
  f32x4 rg[16];          // staging regs (static idx)

  auto load_tile = [&](int kt) {
    const float* sA = (kt < 8) ? p.u : p.h;
    const int kc = (kt & 7) * 64;
#pragma unroll
    for (int cc = 0; cc < 4; ++cc) {
      const float* gp = sA + (size_t)(rowA0 + cc * 64 + sr) * 512 + kc + sc * 8;
      rg[cc * 2]     = *(const f32x4*)gp;
      rg[cc * 2 + 1] = *(const f32x4*)(gp + 4);
    }
#pragma unroll
    for (int cc = 0; cc < 4; ++cc) {   // cc == gate
      const float* sW = (kt < 8) ? p.W[cc] : p.U[cc];
      const float* gp = sW + (size_t)(nrow0 + sr) * 512 + kc + sc * 8;
      rg[8 + cc * 2]     = *(const f32x4*)gp;
      rg[8 + cc * 2 + 1] = *(const f32x4*)(gp + 4);
    }
  };

  auto write_tile = [&]() {
#pragma unroll
    for (int cc = 0; cc < 4; ++cc)
      *(bf16x8*)(smemA + (cc * 64 + sr) * 128 + wcol) =
          cvt8(rg[cc * 2], rg[cc * 2 + 1]);
#pragma unroll
    for (int cc = 0; cc < 4; ++cc)
      *(bf16x8*)(smemW + (cc * 64 + sr) * 128 + wcol) =
          cvt8(rg[8 + cc * 2], rg[8 + cc * 2 + 1]);
  };

  const int xr = (l & 7) << 4;  // read-side swizzle (row&7 == l&7 everywhere)

  auto compute = [&]() {
#pragma unroll
    for (int kk = 0; kk < 2; ++kk) {
      const int kb = (kk * 64 + (l >> 4) * 16) ^ xr;
      bf16x8 a[8];
#pragma unroll
      for (int mf = 0; mf < 8; ++mf)
        a[mf] = *(const bf16x8*)(smemA + (wm * 128 + mf * 16 + (l & 15)) * 128 + kb);
#pragma unroll
      for (int g = 0; g < 4; ++g) {
        bf16x8 b = *(const bf16x8*)(smemW + (g * 64 + wh * 16 + (l & 15)) * 128 + kb);
#pragma unroll
        for (int mf = 0; mf < 8; ++mf)
          acc[g][mf] = __builtin_amdgcn_mfma_f32_16x16x32_bf16(a[mf], b, acc[g][mf], 0, 0, 0);
      }
    }
  };

  load_tile(0);
  for (int kt = 0; kt < 16; ++kt) {
    write_tile();        // vmcnt-waits in-flight loads, cvt, ds_write
    __syncthreads();     // tiles visible
    if (kt < 15) load_tile(kt + 1);  // latency hides under 64 MFMAs/wave
    compute();
    __syncthreads();     // reads done before next overwrite
  }

  // --- fused epilogue (fp32 c in, fp32 h/c out) ---
  // C/D layout: col = lane&15, row = (lane>>4)*4 + reg   [m89/m91]
  const int lr = (l >> 4) * 4;
  const int lc = l & 15;
  const int hc = nrow0 + wh * 16 + lc;
  const int bcol = wh * 16 + lc;
  const float bzi = biasLDS[0][bcol];
  const float bzf = biasLDS[1][bcol];
  const float bzg = biasLDS[2][bcol];
  const float bzo = biasLDS[3][bcol];
#pragma unroll
  for (int mf = 0; mf < 8; ++mf) {
#pragma unroll
    for (int j = 0; j < 4; ++j) {
      const int row = rowA0 + wm * 128 + mf * 16 + lr + j;
      const float zi = acc[0][mf][j] + bzi;
      const float zf = acc[1][mf][j] + bzf;
      const float zg = acc[2][mf][j] + bzg;
      const float zo = acc[3][mf][j] + bzo;
      const float ig = sigmoidf_(zi);
      const float fg = sigmoidf_(zf);
      const float gg = tanhf(zg);
      const float og = sigmoidf_(zo);
      const size_t idx = (size_t)row * 512 + hc;
      const float cv = p.c[idx];
      const float cn = fg * cv + ig * gg;
      const float hn = og * tanhf(cn);
      p.outh[idx] = hn;
      p.outc[idx] = cn;
    }
  }
}

extern "C" void kernel_launch(void* const* d_in, const int* in_sizes, int n_in,
                              void* d_out, int out_size, void* d_ws, size_t ws_size,
                              hipStream_t stream) {
  Params p;
  p.u = (const float*)d_in[0];
  p.h = (const float*)d_in[1];
  p.c = (const float*)d_in[2];
  p.W[0] = (const float*)d_in[3];
  p.bW[0] = (const float*)d_in[4];
  p.W[1] = (const float*)d_in[5];
  p.bW[1] = (const float*)d_in[6];
  p.W[2] = (const float*)d_in[7];
  p.bW[2] = (const float*)d_in[8];
  p.W[3] = (const float*)d_in[9];
  p.bW[3] = (const float*)d_in[10];
  p.U[0] = (const float*)d_in[11];
  p.U[1] = (const float*)d_in[12];
  p.U[2] = (const float*)d_in[13];
  p.U[3] = (const float*)d_in[14];
  p.bE[0] = (const float*)d_in[15];
  p.bE[1] = (const float*)d_in[16];
  p.bE[2] = (const float*)d_in[17];
  p.bE[3] = (const float*)d_in[18];
  p.outh = (float*)d_out;
  p.outc = (float*)d_out + (size_t)BDIM * HDIM;

  dim3 grid(512);
  dim3 block(512);
  hipLaunchKernelGGL(lstm_cell_kernel, grid, block, 0, stream, p);
}

// Round 5
// 98.954 us; speedup vs baseline: 10.2332x; 10.2332x over previous
//
#include <hip/hip_runtime.h>
#include <hip/hip_bf16.h>
#include <cstddef>
#include <cstdint>

// LSTMCell fused: z = [u|h] @ [W|U]^T + bW + bE ; gates ; c/h update.
// fp32 in / fp32 out; bf16 MFMA internal, fp32 accum.
// R5: bf16 pre-pass into d_ws (X=[u|h] 32MB, Wbf gate-major 4MB, bias 8KB),
//     then m97-style global_load_lds main GEMM: BM=256 x (4 gates x 64 hcol),
//     BK=64, 512 thr / 8 waves, double-buffered 128KB LDS, 1 barrier/K-step.
//     LDS swizzle via pre-swizzled GLOBAL source (linear gload_lds dest +
//     XOR on read — rule #21 involution). No reg-staging, no cvt in loop.
//     R4 lesson: __launch_bounds__(512,2) => 256 VGPR cap, acc128+frags fits.
// Fallback: ws_size too small -> proven R2 kernel (137us).

#define BDIM 16384
#define HDIM 512

typedef __attribute__((ext_vector_type(8))) short bf16x8;
typedef __attribute__((ext_vector_type(4))) float f32x4;

struct Params {
  const float* u;
  const float* h;
  const float* c;
  const float* W[4];
  const float* U[4];
  const float* bW[4];
  const float* bE[4];
  float* outh;
  float* outc;
};

__device__ __forceinline__ float sigmoidf_(float x) {
  return 1.0f / (1.0f + __expf(-x));
}
__device__ __forceinline__ float tanhf_(float x) {
  return 2.0f / (1.0f + __expf(-2.0f * x)) - 1.0f;
}

__device__ __forceinline__ void async16(const void* g, void* l) {
  __builtin_amdgcn_global_load_lds((const __attribute__((address_space(1))) void*)g,
                                   (__attribute__((address_space(3))) void*)l,
                                   16, 0, 0);
}

__device__ __forceinline__ bf16x8 cvt8(f32x4 a, f32x4 b) {
  bf16x8 r;
#pragma unroll
  for (int j = 0; j < 4; ++j) {
    __hip_bfloat16 t = __float2bfloat16(a[j]);
    r[j] = *reinterpret_cast<short*>(&t);
  }
#pragma unroll
  for (int j = 0; j < 4; ++j) {
    __hip_bfloat16 t = __float2bfloat16(b[j]);
    r[4 + j] = *reinterpret_cast<short*>(&t);
  }
  return r;
}

// ---------- pre-pass 1: X = [u|h] -> bf16 [16384][1024] ----------
__global__ void cvt_x_kernel(const float* __restrict__ u, const float* __restrict__ h,
                             __hip_bfloat16* __restrict__ Xbf) {
  const size_t e = ((size_t)blockIdx.x * 512 + threadIdx.x) * 8;  // elem idx
  const int r = (int)(e >> 10);
  const int cidx = (int)(e & 1023);
  const float* s = (cidx < 512) ? (u + (size_t)r * 512 + cidx)
                                : (h + (size_t)r * 512 + (cidx - 512));
  f32x4 v0 = *(const f32x4*)s;
  f32x4 v1 = *(const f32x4*)(s + 4);
  *(bf16x8*)(Xbf + e) = cvt8(v0, v1);
}

// ---------- pre-pass 2: Wbf[g][hcol][k'] bf16 + combined bias ----------
__global__ void cvt_w_kernel(Params p, __hip_bfloat16* __restrict__ Wbf,
                             float* __restrict__ biasC) {
  const size_t gt = (size_t)blockIdx.x * 512 + threadIdx.x;
  const size_t e = gt * 8;
  const int g = (int)(e >> 19);            // 512*1024 = 2^19
  const int rem = (int)(e & 524287);
  const int hcol = rem >> 10;
  const int k = rem & 1023;
  const float* s = (k < 512) ? (p.W[g] + (size_t)hcol * 512 + k)
                             : (p.U[g] + (size_t)hcol * 512 + (k - 512));
  f32x4 v0 = *(const f32x4*)s;
  f32x4 v1 = *(const f32x4*)(s + 4);
  *(bf16x8*)(Wbf + e) = cvt8(v0, v1);
  if (gt < 2048) {
    const int bg = (int)(gt >> 9), hh = (int)(gt & 511);
    biasC[gt] = p.bW[bg][hh] + p.bE[bg][hh];
  }
}

// ---------- main GEMM + fused gates ----------
__launch_bounds__(512, 2)
__global__ void lstm_main_kernel(const __hip_bfloat16* __restrict__ Xbf,
                                 const __hip_bfloat16* __restrict__ Wbf,
                                 const float* __restrict__ biasC,
                                 const float* __restrict__ c,
                                 float* __restrict__ outh,
                                 float* __restrict__ outc) {
  // 2 bufs x (A [256][64] bf16 32KB + W [256][64] bf16 32KB) = 128 KB
  __shared__ char smem[131072];

  const int tid = threadIdx.x;
  const int w   = tid >> 6;   // 0..7
  const int l   = tid & 63;
  const int wm  = w >> 2;     // 0..1 : 128-row half
  const int wh  = w & 3;      // 0..3 : 16-hcol group

  // XCD swizzle: 512 blocks, 8 XCDs -> XCD x owns h_tile x (512KB L2 slice)
  const int swz = (blockIdx.x & 7) * 64 + (blockIdx.x >> 3);
  const int m_tile = swz & 63;
  const int h_tile = swz >> 6;
  const int rowA0 = m_tile * 256;
  const int nrow0 = h_tile * 64;

  const int rsub = l >> 3;                 // 0..7 row-within-8
  const int slot = (l & 7) ^ rsub;         // pre-swizzled source 16B slot
  const int gW = w >> 1;                   // gate staged by this wave
  const int hrel0 = (w & 1) * 32;

  f32x4 acc[4][8] = {};  // [gate][m-frag]

  auto stage = [&](int kt, char* bufA, char* bufW) {
    const int kc = kt * 64;
#pragma unroll
    for (int j = 0; j < 4; ++j) {
      const int rit = w * 32 + j * 8 + rsub;
      const __hip_bfloat16* gp = Xbf + (size_t)(rowA0 + rit) * 1024 + kc + slot * 8;
      async16(gp, bufA + (w * 32 + j * 8) * 128);
    }
#pragma unroll
    for (int j = 0; j < 4; ++j) {
      const int hr = hrel0 + j * 8 + rsub;
      const __hip_bfloat16* gp =
          Wbf + (size_t)(gW * 512 + nrow0 + hr) * 1024 + kc + slot * 8;
      async16(gp, bufW + (w * 32 + j * 8) * 128);
    }
  };

  const int xr = (l & 7) << 4;  // read-side swizzle

  auto compute = [&](const char* bufA, const char* bufW) {
#pragma unroll
    for (int kk = 0; kk < 2; ++kk) {
      const int kb = (kk * 64 + (l >> 4) * 16) ^ xr;
      bf16x8 a[8];
#pragma unroll
      for (int mf = 0; mf < 8; ++mf)
        a[mf] = *(const bf16x8*)(bufA + (wm * 128 + mf * 16 + (l & 15)) * 128 + kb);
#pragma unroll
      for (int g = 0; g < 4; ++g) {
        bf16x8 b = *(const bf16x8*)(bufW + (g * 64 + wh * 16 + (l & 15)) * 128 + kb);
#pragma unroll
        for (int mf = 0; mf < 8; ++mf)
          acc[g][mf] = __builtin_amdgcn_mfma_f32_16x16x32_bf16(a[mf], b, acc[g][mf], 0, 0, 0);
      }
    }
  };

  stage(0, smem, smem + 32768);
  __syncthreads();
  int cur = 0;
  for (int kt = 0; kt < 16; ++kt) {
    char* bA = smem + cur * 65536;
    char* nA = smem + (cur ^ 1) * 65536;
    if (kt < 15) stage(kt + 1, nA, nA + 32768);  // prefetch under MFMAs
    compute(bA, bA + 32768);
    __syncthreads();  // vmcnt(0)+lgkmcnt(0) drain + join, once per K-step
    cur ^= 1;
  }

  // ---- fused epilogue ----
  // C/D layout: col = lane&15, row = (lane>>4)*4 + reg   [m89/m91]
  const int lr = (l >> 4) * 4;
  const int lc = l & 15;
  const int hc = nrow0 + wh * 16 + lc;
  const float bzi = biasC[0 * 512 + hc];
  const float bzf = biasC[1 * 512 + hc];
  const float bzg = biasC[2 * 512 + hc];
  const float bzo = biasC[3 * 512 + hc];
#pragma unroll
  for (int mf = 0; mf < 8; ++mf) {
#pragma unroll
    for (int j = 0; j < 4; ++j) {
      const int row = rowA0 + wm * 128 + mf * 16 + lr + j;
      const float zi = acc[0][mf][j] + bzi;
      const float zf = acc[1][mf][j] + bzf;
      const float zg = acc[2][mf][j] + bzg;
      const float zo = acc[3][mf][j] + bzo;
      const float ig = sigmoidf_(zi);
      const float fg = sigmoidf_(zf);
      const float gg = tanhf_(zg);
      const float og = sigmoidf_(zo);
      const size_t idx = (size_t)row * 512 + hc;
      const float cv = c[idx];
      const float cn = fg * cv + ig * gg;
      const float hn = og * tanhf_(cn);
      outh[idx] = hn;
      outc[idx] = cn;
    }
  }
}

// ---------- fallback: proven R2 kernel (137 us) ----------
__launch_bounds__(256, 2)
__global__ void lstm_legacy_kernel(Params p) {
  __shared__ char smem[32768];
  __shared__ float biasLDS[4][32];

  const int tid = threadIdx.x;
  const int w   = tid >> 6;
  const int l   = tid & 63;
  const int m_tile = blockIdx.x & 127;
  const int h_tile = blockIdx.x >> 7;

  char* smemA = smem;
  char* smemW = smem + 16384;
  const int rowA0 = m_tile * 128;
  const int nrow0 = h_tile * 32;

  if (tid < 128) {
    const int g = tid >> 5, hh = tid & 31;
    const int hc = nrow0 + hh;
    biasLDS[g][hh] = p.bW[g][hc] + p.bE[g][hc];
  }

  const int sr = tid >> 3;
  const int sc = tid & 7;
  const int wcol = (sc * 16) ^ ((sr & 7) << 4);

  f32x4 acc[4][2][2] = {};
  f32x4 rg[16];

  auto load_tile = [&](int kt) {
    const float* sA = (kt < 8) ? p.u : p.h;
    const int kc = (kt & 7) * 64;
#pragma unroll
    for (int cc = 0; cc < 4; ++cc) {
      const float* gp = sA + (size_t)(rowA0 + cc * 32 + sr) * 512 + kc + sc * 8;
      rg[cc * 2]     = *(const f32x4*)gp;
      rg[cc * 2 + 1] = *(const f32x4*)(gp + 4);
    }
#pragma unroll
    for (int cc = 0; cc < 4; ++cc) {
      const float* sW = (kt < 8) ? p.W[cc] : p.U[cc];
      const float* gp = sW + (size_t)(nrow0 + sr) * 512 + kc + sc * 8;
      rg[8 + cc * 2]     = *(const f32x4*)gp;
      rg[8 + cc * 2 + 1] = *(const f32x4*)(gp + 4);
    }
  };

  auto write_tile = [&]() {
#pragma unroll
    for (int cc = 0; cc < 4; ++cc)
      *(bf16x8*)(smemA + (cc * 32 + sr) * 128 + wcol) = cvt8(rg[cc * 2], rg[cc * 2 + 1]);
#pragma unroll
    for (int cc = 0; cc < 4; ++cc)
      *(bf16x8*)(smemW + (cc * 32 + sr) * 128 + wcol) = cvt8(rg[8 + cc * 2], rg[8 + cc * 2 + 1]);
  };

  const int xr = (l & 7) << 4;

  auto compute = [&]() {
#pragma unroll
    for (int kk = 0; kk < 2; ++kk) {
      const int kb = (kk * 64 + (l >> 4) * 16) ^ xr;
      bf16x8 a0 = *(const bf16x8*)(smemA + (w * 32 +      (l & 15)) * 128 + kb);
      bf16x8 a1 = *(const bf16x8*)(smemA + (w * 32 + 16 + (l & 15)) * 128 + kb);
#pragma unroll
      for (int g = 0; g < 4; ++g) {
#pragma unroll
        for (int ni = 0; ni < 2; ++ni) {
          bf16x8 b = *(const bf16x8*)(smemW + (g * 32 + ni * 16 + (l & 15)) * 128 + kb);
          acc[g][0][ni] = __builtin_amdgcn_mfma_f32_16x16x32_bf16(a0, b, acc[g][0][ni], 0, 0, 0);
          acc[g][1][ni] = __builtin_amdgcn_mfma_f32_16x16x32_bf16(a1, b, acc[g][1][ni], 0, 0, 0);
        }
      }
    }
  };

  load_tile(0);
  for (int kt = 0; kt < 16; ++kt) {
    write_tile();
    __syncthreads();
    if (kt < 15) load_tile(kt + 1);
    compute();
    __syncthreads();
  }

  const int lr = (l >> 4) * 4;
  const int lc = l & 15;
#pragma unroll
  for (int mi = 0; mi < 2; ++mi) {
#pragma unroll
    for (int j = 0; j < 4; ++j) {
      const int row = rowA0 + w * 32 + mi * 16 + lr + j;
#pragma unroll
      for (int ni = 0; ni < 2; ++ni) {
        const int hc = nrow0 + ni * 16 + lc;
        const int bcol = ni * 16 + lc;
        const float zi = acc[0][mi][ni][j] + biasLDS[0][bcol];
        const float zf = acc[1][mi][ni][j] + biasLDS[1][bcol];
        const float zg = acc[2][mi][ni][j] + biasLDS[2][bcol];
        const float zo = acc[3][mi][ni][j] + biasLDS[3][bcol];
        const float ig = sigmoidf_(zi);
        const float fg = sigmoidf_(zf);
        const float gg = tanhf_(zg);
        const float og = sigmoidf_(zo);
        const size_t idx = (size_t)row * 512 + hc;
        const float cv = p.c[idx];
        const float cn = fg * cv + ig * gg;
        const float hn = og * tanhf_(cn);
        p.outh[idx] = hn;
        p.outc[idx] = cn;
      }
    }
  }
}

extern "C" void kernel_launch(void* const* d_in, const int* in_sizes, int n_in,
                              void* d_out, int out_size, void* d_ws, size_t ws_size,
                              hipStream_t stream) {
  Params p;
  p.u = (const float*)d_in[0];
  p.h = (const float*)d_in[1];
  p.c = (const float*)d_in[2];
  p.W[0] = (const float*)d_in[3];
  p.bW[0] = (const float*)d_in[4];
  p.W[1] = (const float*)d_in[5];
  p.bW[1] = (const float*)d_in[6];
  p.W[2] = (const float*)d_in[7];
  p.bW[2] = (const float*)d_in[8];
  p.W[3] = (const float*)d_in[9];
  p.bW[3] = (const float*)d_in[10];
  p.U[0] = (const float*)d_in[11];
  p.U[1] = (const float*)d_in[12];
  p.U[2] = (const float*)d_in[13];
  p.U[3] = (const float*)d_in[14];
  p.bE[0] = (const float*)d_in[15];
  p.bE[1] = (const float*)d_in[16];
  p.bE[2] = (const float*)d_in[17];
  p.bE[3] = (const float*)d_in[18];
  p.outh = (float*)d_out;
  p.outc = (float*)d_out + (size_t)BDIM * HDIM;

  const size_t X_BYTES = (size_t)BDIM * 1024 * 2;        // 32 MB
  const size_t W_BYTES = (size_t)4 * 512 * 1024 * 2;     // 4 MB
  const size_t B_BYTES = 2048 * 4;                       // 8 KB
  if (ws_size >= X_BYTES + W_BYTES + B_BYTES) {
    __hip_bfloat16* Xbf = (__hip_bfloat16*)d_ws;
    __hip_bfloat16* Wbf = (__hip_bfloat16*)((char*)d_ws + X_BYTES);
    float* biasC = (float*)((char*)d_ws + X_BYTES + W_BYTES);

    hipLaunchKernelGGL(cvt_x_kernel, dim3(4096), dim3(512), 0, stream, p.u, p.h, Xbf);
    hipLaunchKernelGGL(cvt_w_kernel, dim3(512), dim3(512), 0, stream, p, Wbf, biasC);
    hipLaunchKernelGGL(lstm_main_kernel, dim3(512), dim3(512), 0, stream,
                       Xbf, Wbf, biasC, p.c, p.outh, p.outc);
  } else {
    hipLaunchKernelGGL(lstm_legacy_kernel, dim3(2048), dim3(256), 0, stream, p);
  }
}